// Round 6
// baseline (245.842 us; speedup 1.0000x reference)
//
#include <hip/hip_runtime.h>
#include <math.h>

// Problem constants
#define BQ   8
#define NFQ  4096
#define INQ  512
#define NBQ  2
#define NWQ  320
#define CDQ  384
#define MQ   (BQ*NFQ)              // 32768 rows
#define NTOT (NBQ*NWQ)             // 640
#define DMOD (NBQ*CDQ)             // 768
#define QOUT ((size_t)MQ*(size_t)DMOD)  // perplexity slot

#define THREADS 256
#define BM 64
#define BK 32
#define NCH (INQ/BK)               // 16 chunks

// LDS byte layout: B dbuf 2x20KB only (A comes straight from global)
#define B0B 0
#define B1B 20480
#define SMEMB 40960
// epilogue overlays live inside B0 (only touched after the final barrier;
// the last chunk (kc=15, p=1) reads B1, so B0 is dead by then)
#define SSUMB 0      // float [4][64]
#define AYMB  1024   // float [4][64]
#define AIDXB 2048   // int   [4][64]
#define SCB   3072   // float [64]
#define IDXB  3328   // int   [64]

typedef __attribute__((ext_vector_type(4))) float f32x4;
typedef __attribute__((ext_vector_type(8))) short short8;
typedef __attribute__((ext_vector_type(4))) unsigned int u32x4;
typedef const __attribute__((address_space(1))) unsigned short gas_us;
typedef __attribute__((address_space(3))) unsigned short las_us;

static __device__ __forceinline__ unsigned f2bf(float f) {
    unsigned u = __float_as_uint(f);
    return (u + 0x7FFFu + ((u >> 16) & 1u)) >> 16;   // RNE
}

static __device__ __forceinline__ short8 pack8(float4 a, float4 b) {
    u32x4 u;
    u[0] = f2bf(a.x) | (f2bf(a.y) << 16);
    u[1] = f2bf(a.z) | (f2bf(a.w) << 16);
    u[2] = f2bf(b.x) | (f2bf(b.y) << 16);
    u[3] = f2bf(b.z) | (f2bf(b.w) << 16);
    return __builtin_bit_cast(short8, u);
}

#define DECL_ACC(M) f32x4 acc##M##0={0,0,0,0}, acc##M##1={0,0,0,0}, \
    acc##M##2={0,0,0,0}, acc##M##3={0,0,0,0}, acc##M##4={0,0,0,0}

#define MROW(M) \
  acc##M##0 = __builtin_amdgcn_mfma_f32_16x16x32_bf16(fa##M, fb0, acc##M##0,0,0,0); \
  acc##M##1 = __builtin_amdgcn_mfma_f32_16x16x32_bf16(fa##M, fb1, acc##M##1,0,0,0); \
  acc##M##2 = __builtin_amdgcn_mfma_f32_16x16x32_bf16(fa##M, fb2, acc##M##2,0,0,0); \
  acc##M##3 = __builtin_amdgcn_mfma_f32_16x16x32_bf16(fa##M, fb3, acc##M##3,0,0,0); \
  acc##M##4 = __builtin_amdgcn_mfma_f32_16x16x32_bf16(fa##M, fb4, acc##M##4,0,0,0);

#define ADDB(M) \
  acc##M##0 = acc##M##0 + b0v; acc##M##1 = acc##M##1 + b1v; \
  acc##M##2 = acc##M##2 + b2v; acc##M##3 = acc##M##3 + b3v; \
  acc##M##4 = acc##M##4 + b4v;

// B chunk (32k x 320col bf16) -> LDS via async global_load_lds, width 16.
// LDS logical layout: [col][k] bf16, 64B/col, 16B slot s = kg ^ ((col>>1)&3).
// Source pre-swizzled so linear lane*16 dest lands swizzled (rule 21).
#define STAGE_B(KC, BASE) do { \
  const unsigned short* wp_ = WtB + (KC)*BK; \
  __builtin_amdgcn_global_load_lds((gas_us*)(wp_ + gb0), (las_us*)(smem + (BASE) + lo0), 16, 0, 0); \
  __builtin_amdgcn_global_load_lds((gas_us*)(wp_ + gb1), (las_us*)(smem + (BASE) + lo1), 16, 0, 0); \
  __builtin_amdgcn_global_load_lds((gas_us*)(wp_ + gb2), (las_us*)(smem + (BASE) + lo2), 16, 0, 0); \
  __builtin_amdgcn_global_load_lds((gas_us*)(wp_ + gb3), (las_us*)(smem + (BASE) + lo3), 16, 0, 0); \
  __builtin_amdgcn_global_load_lds((gas_us*)(wp_ + gb4), (las_us*)(smem + (BASE) + lo4), 16, 0, 0); \
} while(0)

// sum+argmax per output row (M,R): row = M*16 + q*4 + R
#define EPI1(M,R) do { \
  const int row_ = M*16 + q*4 + R; \
  const int gm_  = m0 + row_; \
  float s_ = __expf(acc##M##0[R]) + __expf(acc##M##1[R]) + __expf(acc##M##2[R]) \
           + __expf(acc##M##3[R]) + __expf(acc##M##4[R]); \
  s_ += __shfl_xor(s_,1,64); s_ += __shfl_xor(s_,2,64); \
  s_ += __shfl_xor(s_,4,64); s_ += __shfl_xor(s_,8,64); \
  const float* gp_ = gum + (size_t)gm_*NTOT + nb*NWQ + w*80 + c15; \
  float ym_ = acc##M##0[R] + gp_[0]; int yi_ = c15; float yt_; \
  yt_ = acc##M##1[R] + gp_[16]; if (yt_>ym_){ym_=yt_; yi_=16+c15;} \
  yt_ = acc##M##2[R] + gp_[32]; if (yt_>ym_){ym_=yt_; yi_=32+c15;} \
  yt_ = acc##M##3[R] + gp_[48]; if (yt_>ym_){ym_=yt_; yi_=48+c15;} \
  yt_ = acc##M##4[R] + gp_[64]; if (yt_>ym_){ym_=yt_; yi_=64+c15;} \
  yi_ += w*80; \
  { float ov_; int oi_; \
    ov_=__shfl_xor(ym_,1,64); oi_=__shfl_xor(yi_,1,64); if(ov_>ym_||(ov_==ym_&&oi_<yi_)){ym_=ov_;yi_=oi_;} \
    ov_=__shfl_xor(ym_,2,64); oi_=__shfl_xor(yi_,2,64); if(ov_>ym_||(ov_==ym_&&oi_<yi_)){ym_=ov_;yi_=oi_;} \
    ov_=__shfl_xor(ym_,4,64); oi_=__shfl_xor(yi_,4,64); if(ov_>ym_||(ov_==ym_&&oi_<yi_)){ym_=ov_;yi_=oi_;} \
    ov_=__shfl_xor(ym_,8,64); oi_=__shfl_xor(yi_,8,64); if(ov_>ym_||(ov_==ym_&&oi_<yi_)){ym_=ov_;yi_=oi_;} } \
  if (c15 == 0) { \
    ((float*)(smem+SSUMB))[w*64 + row_] = s_; \
    ((float*)(smem+AYMB ))[w*64 + row_] = ym_; \
    ((int*  )(smem+AIDXB))[w*64 + row_] = yi_; } \
} while(0)

// masked marginal accumulation (sc = valid/se per row, from LDS)
#define EPI2(M,R) do { \
  const int row_ = M*16 + q*4 + R; \
  const float sc_ = ((float*)(smem+SCB))[row_]; \
  ca0 = fmaf(__expf(acc##M##0[R]), sc_, ca0); \
  ca1 = fmaf(__expf(acc##M##1[R]), sc_, ca1); \
  ca2 = fmaf(__expf(acc##M##2[R]), sc_, ca2); \
  ca3 = fmaf(__expf(acc##M##3[R]), sc_, ca3); \
  ca4 = fmaf(__expf(acc##M##4[R]), sc_, ca4); \
} while(0)

// ---- W (fp32 [512][640]) -> Wt (bf16 [640][512], transposed) ----
__global__ __launch_bounds__(256) void wcvt(const float* __restrict__ W,
                                            unsigned short* __restrict__ Wt)
{
    __shared__ __align__(16) float sm[64][68];
    const int kb = blockIdx.x, cbk = blockIdx.y;
    const int tid = threadIdx.x;
    const int r = tid >> 2, qq = tid & 3;
    const float* wp = W + (size_t)(kb*64 + r)*NTOT + cbk*64;
    *(float4*)(&sm[r][(qq   )*4]) = *(const float4*)(wp + (qq   )*4);
    *(float4*)(&sm[r][(qq+ 4)*4]) = *(const float4*)(wp + (qq+ 4)*4);
    *(float4*)(&sm[r][(qq+ 8)*4]) = *(const float4*)(wp + (qq+ 8)*4);
    *(float4*)(&sm[r][(qq+12)*4]) = *(const float4*)(wp + (qq+12)*4);
    __syncthreads();
    const int cc = tid >> 2, kq = tid & 3;
    const int k0 = kq * 16;
    const float v0=sm[k0+0][cc],  v1=sm[k0+1][cc],  v2=sm[k0+2][cc],  v3=sm[k0+3][cc],
                v4=sm[k0+4][cc],  v5=sm[k0+5][cc],  v6=sm[k0+6][cc],  v7=sm[k0+7][cc],
                v8=sm[k0+8][cc],  v9=sm[k0+9][cc],  v10=sm[k0+10][cc],v11=sm[k0+11][cc],
                v12=sm[k0+12][cc],v13=sm[k0+13][cc],v14=sm[k0+14][cc],v15=sm[k0+15][cc];
    const unsigned u0 = f2bf(v0)  | (f2bf(v1) <<16), u1 = f2bf(v2)  | (f2bf(v3) <<16),
                   u2 = f2bf(v4)  | (f2bf(v5) <<16), u3 = f2bf(v6)  | (f2bf(v7) <<16),
                   u4 = f2bf(v8)  | (f2bf(v9) <<16), u5 = f2bf(v10) | (f2bf(v11)<<16),
                   u6 = f2bf(v12) | (f2bf(v13)<<16), u7 = f2bf(v14) | (f2bf(v15)<<16);
    unsigned short* op = Wt + (size_t)(cbk*64 + cc)*INQ + kb*64 + k0;
    *(uint4*)(op)     = make_uint4(u0,u1,u2,u3);
    *(uint4*)(op + 8) = make_uint4(u4,u5,u6,u7);
}

__global__ __launch_bounds__(THREADS, 3) void qk1(
    const float* __restrict__ x, const unsigned short* __restrict__ Wt,
    const float* __restrict__ bias, const float* __restrict__ cb,
    const float* __restrict__ gum, const int* __restrict__ maskp,
    float* __restrict__ out, float* __restrict__ partial)
{
    __shared__ __align__(16) char smem[SMEMB];
    const int tid = threadIdx.x;
    const int bid = blockIdx.x;
    const int mb = bid >> 1, nb = bid & 1;   // pair nb-blocks adjacently
    const int m0 = mb * BM;
    const int w = tid >> 6, l = tid & 63, q = l >> 4, c15 = l & 15;

    // ---- B staging constants (5 async loads/thread, pre-swizzled source) ----
    const int sB = tid & 3;
    const int colj0 = (tid      ) >> 2, colj1 = (tid +  256) >> 2,
              colj2 = (tid + 512) >> 2, colj3 = (tid +  768) >> 2,
              colj4 = (tid +1024) >> 2;
    const int kgj0 = sB ^ ((colj0 >> 1) & 3), kgj1 = sB ^ ((colj1 >> 1) & 3),
              kgj2 = sB ^ ((colj2 >> 1) & 3), kgj3 = sB ^ ((colj3 >> 1) & 3),
              kgj4 = sB ^ ((colj4 >> 1) & 3);
    const unsigned short* WtB = Wt + (size_t)nb * NWQ * INQ;
    const int gb0 = colj0*INQ + kgj0*8, gb1 = colj1*INQ + kgj1*8,
              gb2 = colj2*INQ + kgj2*8, gb3 = colj3*INQ + kgj3*8,
              gb4 = colj4*INQ + kgj4*8;
    const int lo0 = (tid      )*16, lo1 = (tid+ 256)*16, lo2 = (tid+ 512)*16,
              lo3 = (tid+ 768)*16, lo4 = (tid+1024)*16;

    // ---- A: direct global loads; lane owns row M*16+c15, k-octet q ----
    const float* xa0 = x + (size_t)(m0 +  0 + c15)*INQ + q*8;
    const float* xa1 = x + (size_t)(m0 + 16 + c15)*INQ + q*8;
    const float* xa2 = x + (size_t)(m0 + 32 + c15)*INQ + q*8;
    const float* xa3 = x + (size_t)(m0 + 48 + c15)*INQ + q*8;

    // ---- B fragment read offsets (kg = q, swizzle slot = kg ^ ((c15>>1)&3)) ----
    const int sw = (c15 >> 1) & 3;
    const int boff = (w*80 + c15)*64 + ((q ^ sw) * 16);

    DECL_ACC(0); DECL_ACC(1); DECL_ACC(2); DECL_ACC(3);
    short8 fa0, fa1, fa2, fa3;

    // prologue: stage B chunk 0; load+convert A chunk 0
    {
        STAGE_B(0, B0B);
        const float4 a0 = *(const float4*)(xa0), a1 = *(const float4*)(xa0 + 4);
        const float4 a2 = *(const float4*)(xa1), a3 = *(const float4*)(xa1 + 4);
        const float4 a4 = *(const float4*)(xa2), a5 = *(const float4*)(xa2 + 4);
        const float4 a6 = *(const float4*)(xa3), a7 = *(const float4*)(xa3 + 4);
        fa0 = pack8(a0, a1); fa1 = pack8(a2, a3);
        fa2 = pack8(a4, a5); fa3 = pack8(a6, a7);
    }
    __syncthreads();   // drains vmcnt -> B chunk 0 resident

#pragma unroll 2
    for (int kc = 0; kc < NCH; ++kc) {
        const int p = kc & 1;
        const int Bcur = p ? B1B : B0B;
        const int Bnx  = p ? B0B : B1B;
        float4 n0, n1, n2, n3, n4, n5, n6, n7;
        if (kc + 1 < NCH) {              // issue next-chunk loads early (T14)
            STAGE_B(kc + 1, Bnx);
            const int ko = (kc + 1) * BK;
            n0 = *(const float4*)(xa0 + ko); n1 = *(const float4*)(xa0 + ko + 4);
            n2 = *(const float4*)(xa1 + ko); n3 = *(const float4*)(xa1 + ko + 4);
            n4 = *(const float4*)(xa2 + ko); n5 = *(const float4*)(xa2 + ko + 4);
            n6 = *(const float4*)(xa3 + ko); n7 = *(const float4*)(xa3 + ko + 4);
        }
        const short8 fb0 = *(const short8*)(smem + Bcur + boff);
        const short8 fb1 = *(const short8*)(smem + Bcur + boff + 1024);
        const short8 fb2 = *(const short8*)(smem + Bcur + boff + 2048);
        const short8 fb3 = *(const short8*)(smem + Bcur + boff + 3072);
        const short8 fb4 = *(const short8*)(smem + Bcur + boff + 4096);
        MROW(0); MROW(1); MROW(2); MROW(3);
        if (kc + 1 < NCH) {              // convert-late (loads covered by MFMA)
            fa0 = pack8(n0, n1); fa1 = pack8(n2, n3);
            fa2 = pack8(n4, n5); fa3 = pack8(n6, n7);
        }
        __syncthreads();                 // drains vmcnt -> next B chunk resident
    }

    // ---- epilogue ----
    const float* bp = bias + nb*NWQ + w*80 + c15;
    const float b0v = bp[0], b1v = bp[16], b2v = bp[32], b3v = bp[48], b4v = bp[64];
    ADDB(0); ADDB(1); ADDB(2); ADDB(3);

    EPI1(0,0); EPI1(0,1); EPI1(0,2); EPI1(0,3);
    EPI1(1,0); EPI1(1,1); EPI1(1,2); EPI1(1,3);
    EPI1(2,0); EPI1(2,1); EPI1(2,2); EPI1(2,3);
    EPI1(3,0); EPI1(3,1); EPI1(3,2); EPI1(3,3);
    __syncthreads();

    if (tid < BM) {
        const int row = tid;
        const float* ssum = (const float*)(smem + SSUMB);
        const float* aym  = (const float*)(smem + AYMB);
        const int*   aidx = (const int*)(smem + AIDXB);
        const float se = ssum[row] + ssum[64+row] + ssum[128+row] + ssum[192+row];
        const float vf = (maskp[m0 + row] == 0) ? 1.0f : 0.0f;
        ((float*)(smem + SCB))[row] = vf / se;
        float bv = aym[row]; int bi = aidx[row];
        float ov; int oi;
        ov = aym[ 64+row]; oi = aidx[ 64+row]; if (ov>bv || (ov==bv && oi<bi)) { bv=ov; bi=oi; }
        ov = aym[128+row]; oi = aidx[128+row]; if (ov>bv || (ov==bv && oi<bi)) { bv=ov; bi=oi; }
        ov = aym[192+row]; oi = aidx[192+row]; if (ov>bv || (ov==bv && oi<bi)) { bv=ov; bi=oi; }
        ((int*)(smem + IDXB))[row] = bi;
    }
    __syncthreads();

    float ca0=0.f, ca1=0.f, ca2=0.f, ca3=0.f, ca4=0.f;
    EPI2(0,0); EPI2(0,1); EPI2(0,2); EPI2(0,3);
    EPI2(1,0); EPI2(1,1); EPI2(1,2); EPI2(1,3);
    EPI2(2,0); EPI2(2,1); EPI2(2,2); EPI2(2,3);
    EPI2(3,0); EPI2(3,1); EPI2(3,2); EPI2(3,3);
    ca0 += __shfl_xor(ca0,16,64); ca0 += __shfl_xor(ca0,32,64);
    ca1 += __shfl_xor(ca1,16,64); ca1 += __shfl_xor(ca1,32,64);
    ca2 += __shfl_xor(ca2,16,64); ca2 += __shfl_xor(ca2,32,64);
    ca3 += __shfl_xor(ca3,16,64); ca3 += __shfl_xor(ca3,32,64);
    ca4 += __shfl_xor(ca4,16,64); ca4 += __shfl_xor(ca4,32,64);
    if (l < 16) {
        float* pp = partial + (size_t)mb*NTOT + nb*NWQ + w*80 + c15;
        pp[0]=ca0; pp[16]=ca1; pp[32]=ca2; pp[48]=ca3; pp[64]=ca4;
    }

    // gather codebook rows -> quantized output
    const float* cbb = cb + (size_t)nb*NWQ*CDQ;
    const int* idxs = (const int*)(smem + IDXB);
    for (int t = tid; t < BM*(CDQ/4); t += THREADS) {
        const int r = t / (CDQ/4);
        const int qq = t - r*(CDQ/4);
        const int idx = idxs[r];
        float4 v = *(const float4*)(cbb + (size_t)idx*CDQ + qq*4);
        *(float4*)(out + (size_t)(m0+r)*DMOD + (size_t)nb*CDQ + qq*4) = v;
    }
}

// Reduce partials -> marginal -> perplexity
__global__ void qk2(const float* __restrict__ partial,
                    const int* __restrict__ maskp,
                    float* __restrict__ out)
{
    __shared__ int   ired[10];
    __shared__ float fred[10];
    __shared__ float s_ms;
    const int tid  = threadIdx.x;        // 0..639
    const int lane = tid & 63;
    const int wid  = tid >> 6;           // 0..9

    int ms = 0;
    for (int i = tid; i < MQ; i += 640) ms += maskp[i];
#pragma unroll
    for (int s = 32; s >= 1; s >>= 1) ms += __shfl_xor(ms, s, 64);
    if (lane == 0) ired[wid] = ms;
    __syncthreads();
    if (tid == 0) {
        int t = 0;
        for (int w = 0; w < 10; ++w) t += ired[w];
        s_ms = (float)t;
    }
    __syncthreads();

    float cs0 = 0.f, cs1 = 0.f, cs2 = 0.f, cs3 = 0.f;
    for (int mbq = 0; mbq < MQ/BM; mbq += 4) {
        cs0 += partial[(size_t)(mbq+0)*NTOT + tid];
        cs1 += partial[(size_t)(mbq+1)*NTOT + tid];
        cs2 += partial[(size_t)(mbq+2)*NTOT + tid];
        cs3 += partial[(size_t)(mbq+3)*NTOT + tid];
    }
    float cs = (cs0 + cs1) + (cs2 + cs3);
    float mar = cs / s_ms;
    float tv = mar * logf(mar + 1e-7f);
#pragma unroll
    for (int s = 32; s >= 1; s >>= 1) tv += __shfl_xor(tv, s, 64);
    if (lane == 0) fred[wid] = tv;
    __syncthreads();
    if (tid == 0) {
        float h0 = fred[0]+fred[1]+fred[2]+fred[3]+fred[4];
        float h1 = fred[5]+fred[6]+fred[7]+fred[8]+fred[9];
        out[QOUT] = expf(-h0) + expf(-h1);
    }
}

extern "C" void kernel_launch(void* const* d_in, const int* in_sizes, int n_in,
                              void* d_out, int out_size, void* d_ws, size_t ws_size,
                              hipStream_t stream) {
    const float* x    = (const float*)d_in[0];
    const float* W    = (const float*)d_in[1];
    const float* bias = (const float*)d_in[2];
    const float* cb   = (const float*)d_in[3];
    const float* gum  = (const float*)d_in[4];
    const int*   mask = (const int*)d_in[5];
    float* out = (float*)d_out;
    float* partial = (float*)d_ws;                 // [512][640] f32 = 1.31 MB
    unsigned short* Wt = (unsigned short*)((char*)d_ws + (size_t)MQ/BM*NTOT*4); // bf16 [640][512]

    wcvt<<<dim3(INQ/64, NTOT/64), 256, 0, stream>>>(W, Wt);
    qk1<<<MQ/BM*NBQ, THREADS, 0, stream>>>(x, Wt, bias, cb, gum, mask, out, partial);
    qk2<<<1, 640, 0, stream>>>(partial, mask, out);
}

// Round 7
// 99.068 us; speedup vs baseline: 2.4816x; 2.4816x over previous
//
#include <hip/hip_runtime.h>
#include <math.h>

// Problem constants
#define BQ   8
#define NFQ  4096
#define INQ  512
#define NBQ  2
#define NWQ  320
#define CDQ  384
#define MQ   (BQ*NFQ)              // 32768 rows
#define NTOT (NBQ*NWQ)             // 640
#define DMOD (NBQ*CDQ)             // 768
#define QOUT ((size_t)MQ*(size_t)DMOD)  // perplexity slot

#define THREADS 256
#define BM 32
#define BK 32
#define NCH (INQ/BK)               // 16 chunks
#define NMB (MQ/BM)                // 1024 row-blocks

// LDS layout (bytes): A dbuf 2x2KB, B single 20KB
#define A0B 0
#define A1B 2048
#define BB  4096
#define SMEMB 24576
// epilogue overlays inside B region (only after final barrier)
#define SSUMB 4096   // float [4][32]
#define AYMB  4608   // float [4][32]
#define AIDXB 5120   // int   [4][32]
#define SCB   5632   // float [32]
#define IDXB  5760   // int   [32]

// workspace layout (bytes) -- total ~1.97 MB (same proven footprint)
#define WT_OFF   0          // bf16 Wt [640][512]  = 655360
#define PART_OFF 655360     // bf16 partial [1024][640] = 1310720
#define CS_OFF   1966080    // f32 colsum [640]
#define MC_OFF   1968640    // int maskcnt [8]

typedef __attribute__((ext_vector_type(4))) float f32x4;
typedef __attribute__((ext_vector_type(8))) short short8;
typedef const __attribute__((address_space(1))) unsigned short gas_us;
typedef __attribute__((address_space(3))) unsigned short las_us;

static __device__ __forceinline__ unsigned f2bf(float f) {
    unsigned u = __float_as_uint(f);
    return (u + 0x7FFFu + ((u >> 16) & 1u)) >> 16;   // RNE
}

static __device__ __forceinline__ uint4 pack8u(float4 a, float4 b) {
    return make_uint4(f2bf(a.x) | (f2bf(a.y) << 16),
                      f2bf(a.z) | (f2bf(a.w) << 16),
                      f2bf(b.x) | (f2bf(b.y) << 16),
                      f2bf(b.z) | (f2bf(b.w) << 16));
}

#define MCOL(M,N) \
  acc##M##N = __builtin_amdgcn_mfma_f32_16x16x32_bf16(fa##M, fb##N, acc##M##N,0,0,0);

// B chunk (32k x 320col bf16) -> LDS via async global_load_lds, width 16.
// LDS logical layout: [col][k] bf16, 64B/col, 16B slot s = kg ^ ((col>>1)&3).
// Source pre-swizzled so linear lane*16 dest lands swizzled.
#define STAGE_B(KC) do { \
  const unsigned short* wp_ = WtB + (KC)*BK; \
  __builtin_amdgcn_global_load_lds((gas_us*)(wp_ + gb0), (las_us*)(smem + BB + lo0), 16, 0, 0); \
  __builtin_amdgcn_global_load_lds((gas_us*)(wp_ + gb1), (las_us*)(smem + BB + lo1), 16, 0, 0); \
  __builtin_amdgcn_global_load_lds((gas_us*)(wp_ + gb2), (las_us*)(smem + BB + lo2), 16, 0, 0); \
  __builtin_amdgcn_global_load_lds((gas_us*)(wp_ + gb3), (las_us*)(smem + BB + lo3), 16, 0, 0); \
  __builtin_amdgcn_global_load_lds((gas_us*)(wp_ + gb4), (las_us*)(smem + BB + lo4), 16, 0, 0); \
} while(0)

// sum+argmax per output row (M,R): row = M*16 + q*4 + R  (rows 0..31)
#define EPI1(M,R) do { \
  const int row_ = M*16 + q*4 + (R); \
  const int gm_  = m0 + row_; \
  float s_ = __expf(acc##M##0[R]) + __expf(acc##M##1[R]) + __expf(acc##M##2[R]) \
           + __expf(acc##M##3[R]) + __expf(acc##M##4[R]); \
  s_ += __shfl_xor(s_,1,64); s_ += __shfl_xor(s_,2,64); \
  s_ += __shfl_xor(s_,4,64); s_ += __shfl_xor(s_,8,64); \
  const float* gp_ = gum + (size_t)gm_*NTOT + nb*NWQ + w*80 + c15; \
  float ym_ = acc##M##0[R] + gp_[0]; int yi_ = c15; float yt_; \
  yt_ = acc##M##1[R] + gp_[16]; if (yt_>ym_){ym_=yt_; yi_=16+c15;} \
  yt_ = acc##M##2[R] + gp_[32]; if (yt_>ym_){ym_=yt_; yi_=32+c15;} \
  yt_ = acc##M##3[R] + gp_[48]; if (yt_>ym_){ym_=yt_; yi_=48+c15;} \
  yt_ = acc##M##4[R] + gp_[64]; if (yt_>ym_){ym_=yt_; yi_=64+c15;} \
  yi_ += w*80; \
  { float ov_; int oi_; \
    ov_=__shfl_xor(ym_,1,64); oi_=__shfl_xor(yi_,1,64); if(ov_>ym_||(ov_==ym_&&oi_<yi_)){ym_=ov_;yi_=oi_;} \
    ov_=__shfl_xor(ym_,2,64); oi_=__shfl_xor(yi_,2,64); if(ov_>ym_||(ov_==ym_&&oi_<yi_)){ym_=ov_;yi_=oi_;} \
    ov_=__shfl_xor(ym_,4,64); oi_=__shfl_xor(yi_,4,64); if(ov_>ym_||(ov_==ym_&&oi_<yi_)){ym_=ov_;yi_=oi_;} \
    ov_=__shfl_xor(ym_,8,64); oi_=__shfl_xor(yi_,8,64); if(ov_>ym_||(ov_==ym_&&oi_<yi_)){ym_=ov_;yi_=oi_;} } \
  if (c15 == 0) { \
    ((float*)(smem+SSUMB))[w*32 + row_] = s_; \
    ((float*)(smem+AYMB ))[w*32 + row_] = ym_; \
    ((int*  )(smem+AIDXB))[w*32 + row_] = yi_; } \
} while(0)

// masked marginal accumulation (sc = valid/se per row, from LDS)
#define EPI2(M,R) do { \
  const int row_ = M*16 + q*4 + (R); \
  const float sc_ = ((float*)(smem+SCB))[row_]; \
  ca0 = fmaf(__expf(acc##M##0[R]), sc_, ca0); \
  ca1 = fmaf(__expf(acc##M##1[R]), sc_, ca1); \
  ca2 = fmaf(__expf(acc##M##2[R]), sc_, ca2); \
  ca3 = fmaf(__expf(acc##M##3[R]), sc_, ca3); \
  ca4 = fmaf(__expf(acc##M##4[R]), sc_, ca4); \
} while(0)

// ---- W (fp32 [512][640]) -> Wt (bf16 [640][512], transposed) ----
__global__ __launch_bounds__(256) void wcvt(const float* __restrict__ W,
                                            unsigned short* __restrict__ Wt)
{
    __shared__ __align__(16) float sm[64][68];
    const int kb = blockIdx.x, cbk = blockIdx.y;
    const int tid = threadIdx.x;
    const int r = tid >> 2, qq = tid & 3;
    const float* wp = W + (size_t)(kb*64 + r)*NTOT + cbk*64;
    *(float4*)(&sm[r][(qq   )*4]) = *(const float4*)(wp + (qq   )*4);
    *(float4*)(&sm[r][(qq+ 4)*4]) = *(const float4*)(wp + (qq+ 4)*4);
    *(float4*)(&sm[r][(qq+ 8)*4]) = *(const float4*)(wp + (qq+ 8)*4);
    *(float4*)(&sm[r][(qq+12)*4]) = *(const float4*)(wp + (qq+12)*4);
    __syncthreads();
    const int cc = tid >> 2, kq = tid & 3;
    const int k0 = kq * 16;
    const float v0=sm[k0+0][cc],  v1=sm[k0+1][cc],  v2=sm[k0+2][cc],  v3=sm[k0+3][cc],
                v4=sm[k0+4][cc],  v5=sm[k0+5][cc],  v6=sm[k0+6][cc],  v7=sm[k0+7][cc],
                v8=sm[k0+8][cc],  v9=sm[k0+9][cc],  v10=sm[k0+10][cc],v11=sm[k0+11][cc],
                v12=sm[k0+12][cc],v13=sm[k0+13][cc],v14=sm[k0+14][cc],v15=sm[k0+15][cc];
    const unsigned u0 = f2bf(v0)  | (f2bf(v1) <<16), u1 = f2bf(v2)  | (f2bf(v3) <<16),
                   u2 = f2bf(v4)  | (f2bf(v5) <<16), u3 = f2bf(v6)  | (f2bf(v7) <<16),
                   u4 = f2bf(v8)  | (f2bf(v9) <<16), u5 = f2bf(v10) | (f2bf(v11)<<16),
                   u6 = f2bf(v12) | (f2bf(v13)<<16), u7 = f2bf(v14) | (f2bf(v15)<<16);
    unsigned short* op = Wt + (size_t)(cbk*64 + cc)*INQ + kb*64 + k0;
    *(uint4*)(op)     = make_uint4(u0,u1,u2,u3);
    *(uint4*)(op + 8) = make_uint4(u4,u5,u6,u7);
}

__global__ __launch_bounds__(THREADS, 4) void qk1(
    const float* __restrict__ x, const unsigned short* __restrict__ Wt,
    const float* __restrict__ bias, const float* __restrict__ cb,
    const float* __restrict__ gum, const int* __restrict__ maskp,
    float* __restrict__ out, unsigned short* __restrict__ partial)
{
    __shared__ __align__(16) char smem[SMEMB];
    const int tid = threadIdx.x;
    const int bid = blockIdx.x;
    const int mb = bid >> 1, nb = bid & 1;   // nb-pairs adjacent (share x rows)
    const int m0 = mb * BM;
    const int w = tid >> 6, l = tid & 63, q = l >> 4, c15 = l & 15;

    // ---- B staging constants (5 async loads/thread over 1280 slots) ----
    const int sB = tid & 3;
    const int colj0 = (tid      ) >> 2, colj1 = (tid +  256) >> 2,
              colj2 = (tid + 512) >> 2, colj3 = (tid +  768) >> 2,
              colj4 = (tid +1024) >> 2;
    const int kgj0 = sB ^ ((colj0 >> 1) & 3), kgj1 = sB ^ ((colj1 >> 1) & 3),
              kgj2 = sB ^ ((colj2 >> 1) & 3), kgj3 = sB ^ ((colj3 >> 1) & 3),
              kgj4 = sB ^ ((colj4 >> 1) & 3);
    const unsigned short* WtB = Wt + (size_t)nb * NWQ * INQ;
    const int gb0 = colj0*INQ + kgj0*8, gb1 = colj1*INQ + kgj1*8,
              gb2 = colj2*INQ + kgj2*8, gb3 = colj3*INQ + kgj3*8,
              gb4 = colj4*INQ + kgj4*8;
    const int lo0 = (tid      )*16, lo1 = (tid+ 256)*16, lo2 = (tid+ 512)*16,
              lo3 = (tid+ 768)*16, lo4 = (tid+1024)*16;

    // ---- A staging (tid<128): row = tid>>2 (0..31), k-octet = tid&3 ----
    const int xrow = tid >> 2, xh = tid & 3;
    const float* xg = x + (size_t)(m0 + xrow)*INQ + xh*8;
    const int axw = xrow*64 + ((xh ^ ((xrow >> 1) & 3)) * 16);

    // ---- fragment read offsets (slot = kg ^ ((row/col >>1)&3)) ----
    const int sw = (c15 >> 1) & 3;
    const int aoff = c15*64 + ((q ^ sw) * 16);            // frag m at +1024*m
    const int boff = (w*80 + c15)*64 + ((q ^ sw) * 16);   // frag n at +1024*n

    f32x4 acc00={0,0,0,0}, acc01={0,0,0,0}, acc02={0,0,0,0}, acc03={0,0,0,0}, acc04={0,0,0,0};
    f32x4 acc10={0,0,0,0}, acc11={0,0,0,0}, acc12={0,0,0,0}, acc13={0,0,0,0}, acc14={0,0,0,0};

    // prologue: stage B(0) async + A(0) via regs
    STAGE_B(0);
    if (tid < 128) {
        const float4 a0 = *(const float4*)(xg), a1 = *(const float4*)(xg + 4);
        *(uint4*)(smem + A0B + axw) = pack8u(a0, a1);
    }
    __syncthreads();   // drains vmcnt -> B(0), A(0) resident

#pragma unroll 2
    for (int kc = 0; kc < NCH; ++kc) {
        const int p = kc & 1;
        const int Acur = p ? A1B : A0B;
        const int Anx  = p ? A0B : A1B;
        const bool more = (kc + 1 < NCH);
        // read this chunk's fragments into regs
        const short8 fa0 = *(const short8*)(smem + Acur + aoff);
        const short8 fa1 = *(const short8*)(smem + Acur + aoff + 1024);
        const short8 fb0 = *(const short8*)(smem + BB + boff);
        const short8 fb1 = *(const short8*)(smem + BB + boff + 1024);
        const short8 fb2 = *(const short8*)(smem + BB + boff + 2048);
        const short8 fb3 = *(const short8*)(smem + BB + boff + 3072);
        const short8 fb4 = *(const short8*)(smem + BB + boff + 4096);
        __syncthreads();                 // all B reads done -> safe to restage
        float4 n0, n1;
        if (more) {
            STAGE_B(kc + 1);             // async into same B buffer
            if (tid < 128) {
                n0 = *(const float4*)(xg + (kc+1)*BK);
                n1 = *(const float4*)(xg + (kc+1)*BK + 4);
            }
        }
        MCOL(0,0); MCOL(0,1); MCOL(0,2); MCOL(0,3); MCOL(0,4);
        MCOL(1,0); MCOL(1,1); MCOL(1,2); MCOL(1,3); MCOL(1,4);
        if (more && tid < 128)
            *(uint4*)(smem + Anx + axw) = pack8u(n0, n1);
        __syncthreads();                 // B(k+1)+A(k+1) resident
    }

    // ---- epilogue ----
    const float* bp = bias + nb*NWQ + w*80 + c15;
    const float b0v = bp[0], b1v = bp[16], b2v = bp[32], b3v = bp[48], b4v = bp[64];
    acc00 = acc00 + b0v; acc01 = acc01 + b1v; acc02 = acc02 + b2v;
    acc03 = acc03 + b3v; acc04 = acc04 + b4v;
    acc10 = acc10 + b0v; acc11 = acc11 + b1v; acc12 = acc12 + b2v;
    acc13 = acc13 + b3v; acc14 = acc14 + b4v;

    EPI1(0,0); EPI1(0,1); EPI1(0,2); EPI1(0,3);
    EPI1(1,0); EPI1(1,1); EPI1(1,2); EPI1(1,3);
    __syncthreads();

    if (tid < BM) {
        const int row = tid;
        const float* ssum = (const float*)(smem + SSUMB);
        const float* aym  = (const float*)(smem + AYMB);
        const int*   aidx = (const int*)(smem + AIDXB);
        const float se = ssum[row] + ssum[32+row] + ssum[64+row] + ssum[96+row];
        const float vf = (maskp[m0 + row] == 0) ? 1.0f : 0.0f;
        ((float*)(smem + SCB))[row] = vf / se;
        float bv = aym[row]; int bi = aidx[row];
        float ov; int oi;
        ov = aym[32+row]; oi = aidx[32+row]; if (ov>bv || (ov==bv && oi<bi)) { bv=ov; bi=oi; }
        ov = aym[64+row]; oi = aidx[64+row]; if (ov>bv || (ov==bv && oi<bi)) { bv=ov; bi=oi; }
        ov = aym[96+row]; oi = aidx[96+row]; if (ov>bv || (ov==bv && oi<bi)) { bv=ov; bi=oi; }
        ((int*)(smem + IDXB))[row] = bi;
    }
    __syncthreads();

    float ca0=0.f, ca1=0.f, ca2=0.f, ca3=0.f, ca4=0.f;
    EPI2(0,0); EPI2(0,1); EPI2(0,2); EPI2(0,3);
    EPI2(1,0); EPI2(1,1); EPI2(1,2); EPI2(1,3);
    ca0 += __shfl_xor(ca0,16,64); ca0 += __shfl_xor(ca0,32,64);
    ca1 += __shfl_xor(ca1,16,64); ca1 += __shfl_xor(ca1,32,64);
    ca2 += __shfl_xor(ca2,16,64); ca2 += __shfl_xor(ca2,32,64);
    ca3 += __shfl_xor(ca3,16,64); ca3 += __shfl_xor(ca3,32,64);
    ca4 += __shfl_xor(ca4,16,64); ca4 += __shfl_xor(ca4,32,64);
    if (l < 16) {
        unsigned short* pp = partial + (size_t)mb*NTOT + nb*NWQ + w*80 + c15;
        pp[0]  = (unsigned short)f2bf(ca0);
        pp[16] = (unsigned short)f2bf(ca1);
        pp[32] = (unsigned short)f2bf(ca2);
        pp[48] = (unsigned short)f2bf(ca3);
        pp[64] = (unsigned short)f2bf(ca4);
    }

    // gather codebook rows -> quantized output
    const float* cbb = cb + (size_t)nb*NWQ*CDQ;
    const int* idxs = (const int*)(smem + IDXB);
    for (int t = tid; t < BM*(CDQ/4); t += THREADS) {
        const int r = t / (CDQ/4);
        const int qq = t - r*(CDQ/4);
        const int idx = idxs[r];
        float4 v = *(const float4*)(cbb + (size_t)idx*CDQ + qq*4);
        *(float4*)(out + (size_t)(m0+r)*DMOD + (size_t)nb*CDQ + qq*4) = v;
    }
}

// stage 1 reduce: 40 blocks sum partial columns; 8 blocks count mask
__global__ __launch_bounds__(256) void qk2a(const unsigned short* __restrict__ partial,
                                            const int* __restrict__ maskp,
                                            float* __restrict__ colsum,
                                            int* __restrict__ maskcnt)
{
    __shared__ float fs[256];
    __shared__ int   is[4];
    const int b = blockIdx.x, tid = threadIdx.x;
    if (b < 40) {
        const int ci = tid & 15, g = tid >> 4;
        const int col = b*16 + ci;
        float s = 0.f;
        for (int r = 0; r < 64; ++r) {
            const unsigned u = partial[(size_t)(g*64 + r)*NTOT + col];
            s += __uint_as_float(u << 16);
        }
        fs[g*16 + ci] = s;
        __syncthreads();
        if (tid < 16) {
            float t = 0.f;
            for (int g2 = 0; g2 < 16; ++g2) t += fs[g2*16 + tid];
            colsum[b*16 + tid] = t;
        }
    } else {
        const int bb = b - 40;
        int ms = 0;
        for (int k2 = 0; k2 < 16; ++k2) ms += maskp[bb*4096 + tid + k2*256];
        for (int s2 = 32; s2 >= 1; s2 >>= 1) ms += __shfl_xor(ms, s2, 64);
        if ((tid & 63) == 0) is[tid >> 6] = ms;
        __syncthreads();
        if (tid == 0) maskcnt[bb] = is[0] + is[1] + is[2] + is[3];
    }
}

// stage 2: marginal -> perplexity
__global__ void qk2b(const float* __restrict__ colsum,
                     const int* __restrict__ maskcnt,
                     float* __restrict__ out)
{
    __shared__ float fred[10];
    __shared__ float s_ms;
    const int tid = threadIdx.x, lane = tid & 63, wid = tid >> 6;
    if (tid == 0) {
        int t = 0;
        for (int i = 0; i < 8; ++i) t += maskcnt[i];
        s_ms = (float)t;
    }
    __syncthreads();
    float mar = colsum[tid] / s_ms;
    float tv = mar * logf(mar + 1e-7f);
    for (int s = 32; s >= 1; s >>= 1) tv += __shfl_xor(tv, s, 64);
    if (lane == 0) fred[wid] = tv;
    __syncthreads();
    if (tid == 0) {
        float h0 = fred[0]+fred[1]+fred[2]+fred[3]+fred[4];
        float h1 = fred[5]+fred[6]+fred[7]+fred[8]+fred[9];
        out[QOUT] = expf(-h0) + expf(-h1);
    }
}

extern "C" void kernel_launch(void* const* d_in, const int* in_sizes, int n_in,
                              void* d_out, int out_size, void* d_ws, size_t ws_size,
                              hipStream_t stream) {
    const float* x    = (const float*)d_in[0];
    const float* W    = (const float*)d_in[1];
    const float* bias = (const float*)d_in[2];
    const float* cb   = (const float*)d_in[3];
    const float* gum  = (const float*)d_in[4];
    const int*   mask = (const int*)d_in[5];
    float* out = (float*)d_out;
    unsigned short* Wt      = (unsigned short*)((char*)d_ws + WT_OFF);
    unsigned short* partial = (unsigned short*)((char*)d_ws + PART_OFF);
    float*          colsum  = (float*)((char*)d_ws + CS_OFF);
    int*            maskcnt = (int*)((char*)d_ws + MC_OFF);

    wcvt<<<dim3(INQ/64, NTOT/64), 256, 0, stream>>>(W, Wt);
    qk1<<<NMB*NBQ, THREADS, 0, stream>>>(x, Wt, bias, cb, gum, mask, out, partial);
    qk2a<<<48, 256, 0, stream>>>(partial, mask, colsum, maskcnt);
    qk2b<<<1, 640, 0, stream>>>(colsum, maskcnt, out);
}

// Round 8
// 77.807 us; speedup vs baseline: 3.1597x; 1.2733x over previous
//
#include <hip/hip_runtime.h>
#include <math.h>

// Problem constants
#define BQ   8
#define NFQ  4096
#define INQ  512
#define NBQ  2
#define NWQ  320
#define CDQ  384
#define MQ   (BQ*NFQ)              // 32768 rows
#define NTOT (NBQ*NWQ)             // 640
#define DMOD (NBQ*CDQ)             // 768
#define QOUT ((size_t)MQ*(size_t)DMOD)  // perplexity slot

#define THREADS 512
#define BM 64
#define BK 32
#define NCH (INQ/BK)               // 16 chunks
#define NMB (MQ/BM)                // 512 row-blocks

// LDS layout (bytes): A dbuf 2x4KB, B dbuf 2x20KB = 48KB
#define A0B 0
#define A1B 4096
#define B0B 8192
#define B1B 28672
#define SMEMB 49152
// epilogue overlays inside B0 region (B0 last read at kc=14; overlays used
// only after the final barrier of kc=15 which reads B1)
#define SSUMB 8192   // float [4][64]
#define AYMB  9216   // float [4][64]
#define AIDXB 10240  // int   [4][64]
#define SCB   11264  // float [64]
#define IDXB  11520  // int   [64]
#define CALB  11776  // float [8][80]

// workspace layout (bytes)
#define WT_OFF   0          // bf16 Wt [640][512]  = 655360
#define PART_OFF 655360     // bf16 partial [512][640] = 655360
#define CS_OFF   1310720    // f32 colsum [640]
#define MC_OFF   1313280    // int maskcnt [8]

typedef __attribute__((ext_vector_type(4))) float f32x4;
typedef __attribute__((ext_vector_type(8))) short short8;
typedef const __attribute__((address_space(1))) unsigned short gas_us;
typedef __attribute__((address_space(3))) unsigned short las_us;

static __device__ __forceinline__ unsigned f2bf(float f) {
    unsigned u = __float_as_uint(f);
    return (u + 0x7FFFu + ((u >> 16) & 1u)) >> 16;   // RNE
}

static __device__ __forceinline__ uint4 pack8u(float4 a, float4 b) {
    return make_uint4(f2bf(a.x) | (f2bf(a.y) << 16),
                      f2bf(a.z) | (f2bf(a.w) << 16),
                      f2bf(b.x) | (f2bf(b.y) << 16),
                      f2bf(b.z) | (f2bf(b.w) << 16));
}

#define MCOL(M,N) \
  acc##M##N = __builtin_amdgcn_mfma_f32_16x16x32_bf16(fa##M, fb##N, acc##M##N,0,0,0);

// B chunk (32k x 320col bf16, 20KB = 1280 x 16B slots) via global_load_lds.
// 512 threads: slots tid, tid+512; tid<256 also slot tid+1024.
// LDS logical: [col][k] bf16, 64B/col, slot j holds k-octet j ^ ((col>>1)&3);
// source pre-swizzled so linear lane*16 dest lands swizzled.
#define STAGE_B(KC, BASE) do { \
  const unsigned short* wp_ = WtB + (KC)*BK; \
  __builtin_amdgcn_global_load_lds((gas_us*)(wp_ + gb0), (las_us*)(smem + (BASE) + lo0), 16, 0, 0); \
  __builtin_amdgcn_global_load_lds((gas_us*)(wp_ + gb1), (las_us*)(smem + (BASE) + lo1), 16, 0, 0); \
  if (tid < 256) \
    __builtin_amdgcn_global_load_lds((gas_us*)(wp_ + gb2), (las_us*)(smem + (BASE) + lo2), 16, 0, 0); \
} while(0)

// sum+argmax per output row (M,R): row = rh*32 + M*16 + q*4 + R
#define EPI1(M,R) do { \
  const int row_ = rh*32 + M*16 + q*4 + (R); \
  const int gm_  = m0 + row_; \
  float s_ = __expf(acc##M##0[R]) + __expf(acc##M##1[R]) + __expf(acc##M##2[R]) \
           + __expf(acc##M##3[R]) + __expf(acc##M##4[R]); \
  s_ += __shfl_xor(s_,1,64); s_ += __shfl_xor(s_,2,64); \
  s_ += __shfl_xor(s_,4,64); s_ += __shfl_xor(s_,8,64); \
  const float* gp_ = gum + (size_t)gm_*NTOT + nb*NWQ + cg*80 + c15; \
  float ym_ = acc##M##0[R] + gp_[0]; int yi_ = c15; float yt_; \
  yt_ = acc##M##1[R] + gp_[16]; if (yt_>ym_){ym_=yt_; yi_=16+c15;} \
  yt_ = acc##M##2[R] + gp_[32]; if (yt_>ym_){ym_=yt_; yi_=32+c15;} \
  yt_ = acc##M##3[R] + gp_[48]; if (yt_>ym_){ym_=yt_; yi_=48+c15;} \
  yt_ = acc##M##4[R] + gp_[64]; if (yt_>ym_){ym_=yt_; yi_=64+c15;} \
  yi_ += cg*80; \
  { float ov_; int oi_; \
    ov_=__shfl_xor(ym_,1,64); oi_=__shfl_xor(yi_,1,64); if(ov_>ym_||(ov_==ym_&&oi_<yi_)){ym_=ov_;yi_=oi_;} \
    ov_=__shfl_xor(ym_,2,64); oi_=__shfl_xor(yi_,2,64); if(ov_>ym_||(ov_==ym_&&oi_<yi_)){ym_=ov_;yi_=oi_;} \
    ov_=__shfl_xor(ym_,4,64); oi_=__shfl_xor(yi_,4,64); if(ov_>ym_||(ov_==ym_&&oi_<yi_)){ym_=ov_;yi_=oi_;} \
    ov_=__shfl_xor(ym_,8,64); oi_=__shfl_xor(yi_,8,64); if(ov_>ym_||(ov_==ym_&&oi_<yi_)){ym_=ov_;yi_=oi_;} } \
  if (c15 == 0) { \
    ((float*)(smem+SSUMB))[cg*64 + row_] = s_; \
    ((float*)(smem+AYMB ))[cg*64 + row_] = ym_; \
    ((int*  )(smem+AIDXB))[cg*64 + row_] = yi_; } \
} while(0)

// masked marginal accumulation (sc = valid/se per row, from LDS)
#define EPI2(M,R) do { \
  const int row_ = rh*32 + M*16 + q*4 + (R); \
  const float sc_ = ((float*)(smem+SCB))[row_]; \
  ca0 = fmaf(__expf(acc##M##0[R]), sc_, ca0); \
  ca1 = fmaf(__expf(acc##M##1[R]), sc_, ca1); \
  ca2 = fmaf(__expf(acc##M##2[R]), sc_, ca2); \
  ca3 = fmaf(__expf(acc##M##3[R]), sc_, ca3); \
  ca4 = fmaf(__expf(acc##M##4[R]), sc_, ca4); \
} while(0)

// ---- W (fp32 [512][640]) -> Wt (bf16 [640][512], transposed) ----
__global__ __launch_bounds__(256) void wcvt(const float* __restrict__ W,
                                            unsigned short* __restrict__ Wt)
{
    __shared__ __align__(16) float sm[64][68];
    const int kb = blockIdx.x, cbk = blockIdx.y;
    const int tid = threadIdx.x;
    const int r = tid >> 2, qq = tid & 3;
    const float* wp = W + (size_t)(kb*64 + r)*NTOT + cbk*64;
    *(float4*)(&sm[r][(qq   )*4]) = *(const float4*)(wp + (qq   )*4);
    *(float4*)(&sm[r][(qq+ 4)*4]) = *(const float4*)(wp + (qq+ 4)*4);
    *(float4*)(&sm[r][(qq+ 8)*4]) = *(const float4*)(wp + (qq+ 8)*4);
    *(float4*)(&sm[r][(qq+12)*4]) = *(const float4*)(wp + (qq+12)*4);
    __syncthreads();
    const int cc = tid >> 2, kq = tid & 3;
    const int k0 = kq * 16;
    const float v0=sm[k0+0][cc],  v1=sm[k0+1][cc],  v2=sm[k0+2][cc],  v3=sm[k0+3][cc],
                v4=sm[k0+4][cc],  v5=sm[k0+5][cc],  v6=sm[k0+6][cc],  v7=sm[k0+7][cc],
                v8=sm[k0+8][cc],  v9=sm[k0+9][cc],  v10=sm[k0+10][cc],v11=sm[k0+11][cc],
                v12=sm[k0+12][cc],v13=sm[k0+13][cc],v14=sm[k0+14][cc],v15=sm[k0+15][cc];
    const unsigned u0 = f2bf(v0)  | (f2bf(v1) <<16), u1 = f2bf(v2)  | (f2bf(v3) <<16),
                   u2 = f2bf(v4)  | (f2bf(v5) <<16), u3 = f2bf(v6)  | (f2bf(v7) <<16),
                   u4 = f2bf(v8)  | (f2bf(v9) <<16), u5 = f2bf(v10) | (f2bf(v11)<<16),
                   u6 = f2bf(v12) | (f2bf(v13)<<16), u7 = f2bf(v14) | (f2bf(v15)<<16);
    unsigned short* op = Wt + (size_t)(cbk*64 + cc)*INQ + kb*64 + k0;
    *(uint4*)(op)     = make_uint4(u0,u1,u2,u3);
    *(uint4*)(op + 8) = make_uint4(u4,u5,u6,u7);
}

__global__ __launch_bounds__(THREADS, 4) void qk1(
    const float* __restrict__ x, const unsigned short* __restrict__ Wt,
    const float* __restrict__ bias, const float* __restrict__ cb,
    const float* __restrict__ gum, const int* __restrict__ maskp,
    float* __restrict__ out, unsigned short* __restrict__ partial)
{
    __shared__ __align__(16) char smem[SMEMB];
    const int tid = threadIdx.x;
    const int bid = blockIdx.x;
    const int mb = bid >> 1, nb = bid & 1;   // nb-pairs adjacent (share x rows)
    const int m0 = mb * BM;
    const int w = tid >> 6, l = tid & 63, q = l >> 4, c15 = l & 15;
    const int cg = w & 3, rh = w >> 2;       // col-group (80 cols), row-half (32 rows)

    // ---- B staging constants (slots tid, tid+512, tid+1024<256) ----
    const int sB = tid & 3;
    const int colj0 = (tid      ) >> 2, colj1 = (tid +  512) >> 2,
              colj2 = (tid + 1024) >> 2;
    const int kgj0 = sB ^ ((colj0 >> 1) & 3), kgj1 = sB ^ ((colj1 >> 1) & 3),
              kgj2 = sB ^ ((colj2 >> 1) & 3);
    const unsigned short* WtB = Wt + (size_t)nb * NWQ * INQ;
    const int gb0 = colj0*INQ + kgj0*8, gb1 = colj1*INQ + kgj1*8,
              gb2 = colj2*INQ + kgj2*8;
    const int lo0 = (tid      )*16, lo1 = (tid+ 512)*16, lo2 = (tid+1024)*16;

    // ---- A staging (tid<256): row = tid>>2 (0..63), k-octet = tid&3 ----
    const int xrow = tid >> 2, xh = tid & 3;
    const float* xg = x + (size_t)(m0 + xrow)*INQ + xh*8;
    const int axw = xrow*64 + ((xh ^ ((xrow >> 1) & 3)) * 16);

    // ---- fragment read offsets (slot = q ^ ((row/col >>1)&3)) ----
    const int sw = (c15 >> 1) & 3;           // same for A row & B col (cg*80 ≡ 0 mod 8)
    const int aoff = (rh*32 + c15)*64 + ((q ^ sw) * 16);   // frag m at +1024*m
    const int boff = (cg*80 + c15)*64 + ((q ^ sw) * 16);   // frag n at +1024*n

    f32x4 acc00={0,0,0,0}, acc01={0,0,0,0}, acc02={0,0,0,0}, acc03={0,0,0,0}, acc04={0,0,0,0};
    f32x4 acc10={0,0,0,0}, acc11={0,0,0,0}, acc12={0,0,0,0}, acc13={0,0,0,0}, acc14={0,0,0,0};

    // prologue: stage B(0)->B0, A(0)->A0
    STAGE_B(0, B0B);
    if (tid < 256) {
        const float4 a0 = *(const float4*)(xg), a1 = *(const float4*)(xg + 4);
        *(uint4*)(smem + A0B + axw) = pack8u(a0, a1);
    }
    __syncthreads();   // drains vmcnt -> B(0), A(0) resident

#pragma unroll 2
    for (int kc = 0; kc < NCH; ++kc) {
        const int p = kc & 1;
        const int Acur = p ? A1B : A0B;
        const int Anx  = p ? A0B : A1B;
        const int Bcur = p ? B1B : B0B;
        const int Bnx  = p ? B0B : B1B;
        const bool more = (kc + 1 < NCH);
        float4 n0, n1;
        if (more) {                      // issue next-chunk loads FIRST (T14)
            if (tid < 256) {
                n0 = *(const float4*)(xg + (kc+1)*BK);
                n1 = *(const float4*)(xg + (kc+1)*BK + 4);
            }
            STAGE_B(kc + 1, Bnx);
        }
        const short8 fa0 = *(const short8*)(smem + Acur + aoff);
        const short8 fa1 = *(const short8*)(smem + Acur + aoff + 1024);
        const short8 fb0 = *(const short8*)(smem + Bcur + boff);
        const short8 fb1 = *(const short8*)(smem + Bcur + boff + 1024);
        const short8 fb2 = *(const short8*)(smem + Bcur + boff + 2048);
        const short8 fb3 = *(const short8*)(smem + Bcur + boff + 3072);
        const short8 fb4 = *(const short8*)(smem + Bcur + boff + 4096);
        MCOL(0,0); MCOL(0,1); MCOL(0,2); MCOL(0,3); MCOL(0,4);
        MCOL(1,0); MCOL(1,1); MCOL(1,2); MCOL(1,3); MCOL(1,4);
        if (more && tid < 256)
            *(uint4*)(smem + Anx + axw) = pack8u(n0, n1);
        __syncthreads();                 // ONE barrier/chunk: next bufs resident
    }

    // ---- epilogue ----
    const float* bp = bias + nb*NWQ + cg*80 + c15;
    const float b0v = bp[0], b1v = bp[16], b2v = bp[32], b3v = bp[48], b4v = bp[64];
    acc00 = acc00 + b0v; acc01 = acc01 + b1v; acc02 = acc02 + b2v;
    acc03 = acc03 + b3v; acc04 = acc04 + b4v;
    acc10 = acc10 + b0v; acc11 = acc11 + b1v; acc12 = acc12 + b2v;
    acc13 = acc13 + b3v; acc14 = acc14 + b4v;

    EPI1(0,0); EPI1(0,1); EPI1(0,2); EPI1(0,3);
    EPI1(1,0); EPI1(1,1); EPI1(1,2); EPI1(1,3);
    __syncthreads();

    if (tid < BM) {
        const int row = tid;
        const float* ssum = (const float*)(smem + SSUMB);
        const float* aym  = (const float*)(smem + AYMB);
        const int*   aidx = (const int*)(smem + AIDXB);
        const float se = ssum[row] + ssum[64+row] + ssum[128+row] + ssum[192+row];
        const float vf = (maskp[m0 + row] == 0) ? 1.0f : 0.0f;
        ((float*)(smem + SCB))[row] = vf / se;
        float bv = aym[row]; int bi = aidx[row];
        float ov; int oi;
        ov = aym[ 64+row]; oi = aidx[ 64+row]; if (ov>bv || (ov==bv && oi<bi)) { bv=ov; bi=oi; }
        ov = aym[128+row]; oi = aidx[128+row]; if (ov>bv || (ov==bv && oi<bi)) { bv=ov; bi=oi; }
        ov = aym[192+row]; oi = aidx[192+row]; if (ov>bv || (ov==bv && oi<bi)) { bv=ov; bi=oi; }
        ((int*)(smem + IDXB))[row] = bi;
    }
    __syncthreads();

    float ca0=0.f, ca1=0.f, ca2=0.f, ca3=0.f, ca4=0.f;
    EPI2(0,0); EPI2(0,1); EPI2(0,2); EPI2(0,3);
    EPI2(1,0); EPI2(1,1); EPI2(1,2); EPI2(1,3);
    ca0 += __shfl_xor(ca0,16,64); ca0 += __shfl_xor(ca0,32,64);
    ca1 += __shfl_xor(ca1,16,64); ca1 += __shfl_xor(ca1,32,64);
    ca2 += __shfl_xor(ca2,16,64); ca2 += __shfl_xor(ca2,32,64);
    ca3 += __shfl_xor(ca3,16,64); ca3 += __shfl_xor(ca3,32,64);
    ca4 += __shfl_xor(ca4,16,64); ca4 += __shfl_xor(ca4,32,64);
    // combine the two row-halves (waves w and w+4 cover same cols)
    if (l < 16) {
        float* cal = (float*)(smem + CALB) + w*80 + c15;
        cal[0]=ca0; cal[16]=ca1; cal[32]=ca2; cal[48]=ca3; cal[64]=ca4;
    }
    __syncthreads();
    if (tid < NWQ) {
        const float* cal = (const float*)(smem + CALB);
        const float v = cal[tid] + cal[tid + 320];
        partial[(size_t)mb*NTOT + nb*NWQ + tid] = (unsigned short)f2bf(v);
    }

    // gather codebook rows -> quantized output
    const float* cbb = cb + (size_t)nb*NWQ*CDQ;
    const int* idxs = (const int*)(smem + IDXB);
    for (int t = tid; t < BM*(CDQ/4); t += THREADS) {
        const int r = t / (CDQ/4);
        const int qq = t - r*(CDQ/4);
        const int idx = idxs[r];
        float4 v = *(const float4*)(cbb + (size_t)idx*CDQ + qq*4);
        *(float4*)(out + (size_t)(m0+r)*DMOD + (size_t)nb*CDQ + qq*4) = v;
    }
}

// stage 1 reduce: 40 blocks sum partial columns; 8 blocks count mask
__global__ __launch_bounds__(256) void qk2a(const unsigned short* __restrict__ partial,
                                            const int* __restrict__ maskp,
                                            float* __restrict__ colsum,
                                            int* __restrict__ maskcnt)
{
    __shared__ float fs[256];
    __shared__ int   is[4];
    const int b = blockIdx.x, tid = threadIdx.x;
    if (b < 40) {
        const int ci = tid & 15, g = tid >> 4;
        const int col = b*16 + ci;
        float s = 0.f;
        for (int r = 0; r < 32; ++r) {
            const unsigned u = partial[(size_t)(g*32 + r)*NTOT + col];
            s += __uint_as_float(u << 16);
        }
        fs[g*16 + ci] = s;
        __syncthreads();
        if (tid < 16) {
            float t = 0.f;
            for (int g2 = 0; g2 < 16; ++g2) t += fs[g2*16 + tid];
            colsum[b*16 + tid] = t;
        }
    } else {
        const int bb = b - 40;
        int ms = 0;
        for (int k2 = 0; k2 < 16; ++k2) ms += maskp[bb*4096 + tid + k2*256];
        for (int s2 = 32; s2 >= 1; s2 >>= 1) ms += __shfl_xor(ms, s2, 64);
        if ((tid & 63) == 0) is[tid >> 6] = ms;
        __syncthreads();
        if (tid == 0) maskcnt[bb] = is[0] + is[1] + is[2] + is[3];
    }
}

// stage 2: marginal -> perplexity
__global__ void qk2b(const float* __restrict__ colsum,
                     const int* __restrict__ maskcnt,
                     float* __restrict__ out)
{
    __shared__ float fred[10];
    __shared__ float s_ms;
    const int tid = threadIdx.x, lane = tid & 63, wid = tid >> 6;
    if (tid == 0) {
        int t = 0;
        for (int i = 0; i < 8; ++i) t += maskcnt[i];
        s_ms = (float)t;
    }
    __syncthreads();
    float mar = colsum[tid] / s_ms;
    float tv = mar * logf(mar + 1e-7f);
    for (int s = 32; s >= 1; s >>= 1) tv += __shfl_xor(tv, s, 64);
    if (lane == 0) fred[wid] = tv;
    __syncthreads();
    if (tid == 0) {
        float h0 = fred[0]+fred[1]+fred[2]+fred[3]+fred[4];
        float h1 = fred[5]+fred[6]+fred[7]+fred[8]+fred[9];
        out[QOUT] = expf(-h0) + expf(-h1);
    }
}

extern "C" void kernel_launch(void* const* d_in, const int* in_sizes, int n_in,
                              void* d_out, int out_size, void* d_ws, size_t ws_size,
                              hipStream_t stream) {
    const float* x    = (const float*)d_in[0];
    const float* W    = (const float*)d_in[1];
    const float* bias = (const float*)d_in[2];
    const float* cb   = (const float*)d_in[3];
    const float* gum  = (const float*)d_in[4];
    const int*   mask = (const int*)d_in[5];
    float* out = (float*)d_out;
    unsigned short* Wt      = (unsigned short*)((char*)d_ws + WT_OFF);
    unsigned short* partial = (unsigned short*)((char*)d_ws + PART_OFF);
    float*          colsum  = (float*)((char*)d_ws + CS_OFF);
    int*            maskcnt = (int*)((char*)d_ws + MC_OFF);

    wcvt<<<dim3(INQ/64, NTOT/64), 256, 0, stream>>>(W, Wt);
    qk1<<<NMB*NBQ, THREADS, 0, stream>>>(x, Wt, bias, cb, gum, mask, out, partial);
    qk2a<<<48, 256, 0, stream>>>(partial, mask, colsum, maskcnt);
    qk2b<<<1, 640, 0, stream>>>(colsum, maskcnt, out);
}